// Round 10
// baseline (11866.409 us; speedup 1.0000x reference)
//
#include <hip/hip_runtime.h>
#include <hip/hip_bf16.h>

#define T_LEN 256
#define B_DIM 128
#define I_DIM 256
#define H_DIM 1024

typedef __attribute__((ext_vector_type(8))) short short8;
typedef __attribute__((ext_vector_type(4))) float f32x4;
typedef __attribute__((ext_vector_type(4))) unsigned uint32x4;

// RNE float->bf16 (self-contained; inputs here are never NaN)
static __device__ __forceinline__ unsigned short f2bf(float f) {
  unsigned u = __float_as_uint(f);
  return (unsigned short)((u + 0x7fffu + ((u >> 16) & 1u)) >> 16);
}
static __device__ __forceinline__ float bf2f(unsigned short h) {
  return __uint_as_float((unsigned)h << 16);
}

// ---------------------------------------------------------------------------
// Phase 1a (fallback): x_proj GEMM fp32 (proven, used when ws is small).
// ---------------------------------------------------------------------------
__global__ __launch_bounds__(256) void xproj_gemm(
    const float* __restrict__ A, const float* __restrict__ W,
    const float* __restrict__ bias, float* __restrict__ C) {
  __shared__ float As[64][33];
  __shared__ float Ws[64][33];

  const int tid = threadIdx.x;
  const int m0 = blockIdx.y * 64;
  const int n0 = blockIdx.x * 64;
  const int ty = tid >> 4;
  const int tx = tid & 15;
  const int r   = tid >> 3;
  const int c4  = (tid & 7) << 2;

  float acc[4][4] = {};

  for (int kc = 0; kc < I_DIM; kc += 32) {
#pragma unroll
    for (int p = 0; p < 2; ++p) {
      const int rr = r + p * 32;
      const float4 a = *(const float4*)(A + (size_t)(m0 + rr) * I_DIM + kc + c4);
      As[rr][c4 + 0] = a.x; As[rr][c4 + 1] = a.y;
      As[rr][c4 + 2] = a.z; As[rr][c4 + 3] = a.w;
      const float4 w = *(const float4*)(W + (size_t)(n0 + rr) * I_DIM + kc + c4);
      Ws[rr][c4 + 0] = w.x; Ws[rr][c4 + 1] = w.y;
      Ws[rr][c4 + 2] = w.z; Ws[rr][c4 + 3] = w.w;
    }
    __syncthreads();
#pragma unroll
    for (int k = 0; k < 32; ++k) {
      float av[4], wv[4];
#pragma unroll
      for (int i = 0; i < 4; ++i) av[i] = As[ty * 4 + i][k];
#pragma unroll
      for (int j = 0; j < 4; ++j) wv[j] = Ws[tx * 4 + j][k];
#pragma unroll
      for (int i = 0; i < 4; ++i)
#pragma unroll
        for (int j = 0; j < 4; ++j)
          acc[i][j] = fmaf(av[i], wv[j], acc[i][j]);
    }
    __syncthreads();
  }

  const float4 bv = *(const float4*)(bias + n0 + tx * 4);
#pragma unroll
  for (int i = 0; i < 4; ++i) {
    float4 o;
    o.x = acc[i][0] + bv.x;
    o.y = acc[i][1] + bv.y;
    o.z = acc[i][2] + bv.z;
    o.w = acc[i][3] + bv.w;
    *(float4*)(C + (size_t)(m0 + ty * 4 + i) * H_DIM + n0 + tx * 4) = o;
  }
}

// ---------------------------------------------------------------------------
// Phase 1b: x_proj via split-bf16 MFMA (r6-proven, absmax unchanged).
// ---------------------------------------------------------------------------
__global__ __launch_bounds__(256) void cvt_hi_lo(
    const float* __restrict__ X, unsigned short* __restrict__ Xh,
    unsigned short* __restrict__ Xl) {
  const int i4 = blockIdx.x * 256 + threadIdx.x;     // one float4 per thread
  const float4 x = ((const float4*)X)[i4];
  ushort4 h, l;
  h.x = f2bf(x.x); l.x = f2bf(x.x - bf2f(h.x));
  h.y = f2bf(x.y); l.y = f2bf(x.y - bf2f(h.y));
  h.z = f2bf(x.z); l.z = f2bf(x.z - bf2f(h.z));
  h.w = f2bf(x.w); l.w = f2bf(x.w - bf2f(h.w));
  ((ushort4*)Xh)[i4] = h;
  ((ushort4*)Xl)[i4] = l;
}

__global__ __launch_bounds__(256) void xproj_mfma(
    const unsigned short* __restrict__ Ah, const unsigned short* __restrict__ Al,
    const unsigned short* __restrict__ Wh, const unsigned short* __restrict__ Wl,
    const float* __restrict__ bias, float* __restrict__ C) {
  const int tid  = threadIdx.x;
  const int wv   = tid >> 6;
  const int lane = tid & 63;
  const int ln   = lane & 15;
  const int q    = lane >> 4;
  const int mw   = wv >> 1;                 // 0..1
  const int nw   = wv & 1;                  // 0..1
  const int m0   = blockIdx.y * 128 + mw * 64;
  const int n0   = blockIdx.x * 64  + nw * 32;

  f32x4 acc[4][2] = {};

#pragma unroll
  for (int kc = 0; kc < 8; ++kc) {          // K = 256 = 8 x 32
    const int ko = kc * 32 + q * 8;
    short8 afh[4], afl[4], wfh[2], wfl[2];
#pragma unroll
    for (int fm = 0; fm < 4; ++fm) {
      const size_t off = (size_t)(m0 + fm * 16 + ln) * I_DIM + ko;
      afh[fm] = *(const short8*)(Ah + off);
      afl[fm] = *(const short8*)(Al + off);
    }
#pragma unroll
    for (int fn = 0; fn < 2; ++fn) {
      const size_t off = (size_t)(n0 + fn * 16 + ln) * I_DIM + ko;
      wfh[fn] = *(const short8*)(Wh + off);
      wfl[fn] = *(const short8*)(Wl + off);
    }
#pragma unroll
    for (int fm = 0; fm < 4; ++fm)
#pragma unroll
      for (int fn = 0; fn < 2; ++fn) {
        acc[fm][fn] = __builtin_amdgcn_mfma_f32_16x16x32_bf16(afh[fm], wfh[fn], acc[fm][fn], 0, 0, 0);
        acc[fm][fn] = __builtin_amdgcn_mfma_f32_16x16x32_bf16(afh[fm], wfl[fn], acc[fm][fn], 0, 0, 0);
        acc[fm][fn] = __builtin_amdgcn_mfma_f32_16x16x32_bf16(afl[fm], wfh[fn], acc[fm][fn], 0, 0, 0);
      }
  }

  // D layout: col (j) = lane&15, row (m) = (lane>>4)*4 + reg.
#pragma unroll
  for (int fn = 0; fn < 2; ++fn) {
    const int j = n0 + fn * 16 + ln;
    const float bj = bias[j];
#pragma unroll
    for (int fm = 0; fm < 4; ++fm)
#pragma unroll
      for (int r = 0; r < 4; ++r)
        C[(size_t)(m0 + fm * 16 + q * 4 + r) * H_DIM + j] = acc[fm][fn][r] + bj;
  }
}

// ---------------------------------------------------------------------------
// One-time converts: W_hh -> bf16 [j][k]; hTag init.
// hTag word = (step_tag << 16) | bf16(value). parity0 = tag 0 + h0 bcast;
// parity1 = sentinel tag 0xFFFF (never matches an expected tag 1..256, and
// overwrites any ws poison that could false-validate).
// ---------------------------------------------------------------------------
__global__ __launch_bounds__(256) void cvt_w_bf16(
    const float* __restrict__ W, unsigned short* __restrict__ Wb) {
  const int i4 = blockIdx.x * 256 + threadIdx.x;
  const float4 w = ((const float4*)W)[i4];
  ushort4 o;
  o.x = f2bf(w.x); o.y = f2bf(w.y); o.z = f2bf(w.z); o.w = f2bf(w.w);
  ((ushort4*)Wb)[i4] = o;
}

__global__ __launch_bounds__(256) void init_htag(
    const float* __restrict__ h0, unsigned* __restrict__ hTag) {
  const int idx = blockIdx.x * 256 + threadIdx.x;    // [0, 131072)
  hTag[idx] = (unsigned)f2bf(h0[idx & (H_DIM - 1)]);
  hTag[(size_t)(B_DIM * H_DIM) + idx] = 0xFFFF0000u;
}

// ---------------------------------------------------------------------------
// Phase 2: persistent cooperative kernel — round-10 tagged-h protocol.
// Grid 64 = 4 b-quarter clusters x 16 j-tiles (64 j). Block 512 thr =
// 8 waves: wave -> m-tile mt=wv>>2 (16 b) x k-quarter kq=wv&3 (256 k).
//
// Protocol (replaces flags/polls/drains entirely):
//  - h element = dword (tag<<16)|bf16, ping-pong by parity. Producer's
//    epilogue stores each element tagged t+1 (WT relaxed-agent) — posts
//    NOTHING else, drains NOTHING.
//  - Consumer loads its h chunk (sc0 sc1, L3-coherent) and validates all
//    tags == t in registers; on mismatch, re-issues the batch. Detection
//    and data transfer are the SAME L3 round-trip (r9 paid 3 extra:
//    drain, flag visibility, separate poll).
//  - Safety: block p overwrites parity P (holding tag t-1) during its
//    step-t epilogue only after p validated tag t across its FULL k-range
//    (all 32 cluster... all 16 producer blocks + both mt waves) — which
//    proves every cluster block finished its tag-(t-1) reads (writes
//    follow reads in program order). No stale-read, no deadlock.
//  - W_hh block slice (64j x 1024k bf16 = 128 KB) staged to LDS ONCE;
//    read via conflict-free lane-linear ds_read_b128. No VGPR spill
//    (r9's killer: VGPR_Count=96 proved wfrag lived in scratch), no
//    per-step W traffic (r8's killer).
//  - x[t] prefetch issued BEFORE the validate loop: its vmcnt(0) drains
//    x for free; epilogue uses registers, no waits.
//  - red[] reduction guarded by 2 intra-block barriers (LDS too tight
//    for parity-double-buffer alongside 128 KB W).
// ---------------------------------------------------------------------------
__global__ __launch_bounds__(512, 1) void rnn_persist(
    unsigned* __restrict__ hTag,                // 2 x [128][1024] tagged dwords
    const unsigned short* __restrict__ Wb,      // [1024][1024] bf16
    const float* __restrict__ b_hh,
    const float* __restrict__ h0,
    float* __restrict__ out)                    // [T][B][H]: in x_proj, out h_t
{
  __shared__ short8 w_lds[4 * 8 * 4 * 64];      // 128 KB: [(kq*8+kc)*4+jf][lane]
  __shared__ float red[3][2][16][65];           // 24.9 KB: [kq-1][mt][bl][jl]

  const int tid  = threadIdx.x;
  const int wv   = tid >> 6;         // 0..7
  const int lane = tid & 63;
  const int ln   = lane & 15;        // A: b-row / B: j-row / D: j-col
  const int q    = lane >> 4;        // 0..3

  const int bid = blockIdx.x;        // 0..63
  const int bq  = bid >> 4;          // cluster (batch quarter)
  const int lj  = bid & 15;          // j-tile (64 j)
  const int j0  = lj * 64;
  const int mt  = wv >> 2;
  const int kq  = wv & 3;
  const int b0  = bq * 32 + mt * 16;

  // ---- stage W slice to LDS (once): 128 chunks of 1 KB; 16 per wave ----
  {
#pragma unroll
    for (int ci = 0; ci < 16; ++ci) {
      const int c   = wv * 16 + ci;
      const int ckq = c >> 5;
      const int ckc = (c >> 2) & 7;
      const int cjf = c & 3;
      const short8* src = (const short8*)(Wb
          + (size_t)(j0 + cjf * 16 + ln) * H_DIM + ckq * 256 + ckc * 32 + q * 8);
      w_lds[c * 64 + lane] = *src;
    }
  }

  const size_t HT = (size_t)B_DIM * H_DIM;     // 131072
  const unsigned* __restrict__ hrow =
      hTag + (size_t)(b0 + ln) * H_DIM + kq * 256 + q * 8;

  const bool epi = (kq == 0);        // waves 0,4: epilogue owners (per mt)
  float bj[4], hcur[4][4];
  size_t obase = 0;
  if (epi) {
    obase = (size_t)(b0 + q * 4) * H_DIM + j0 + ln;
#pragma unroll
    for (int jf = 0; jf < 4; ++jf) {
      bj[jf] = b_hh[j0 + jf * 16 + ln];
      const float h0j = h0[j0 + jf * 16 + ln];
#pragma unroll
      for (int r = 0; r < 4; ++r) hcur[jf][r] = h0j;
    }
  }
  __syncthreads();   // W staged

  for (int t = 0; t < T_LEN; ++t) {
    const unsigned tagpat = (unsigned)t << 16;

    // ---- x[t] prefetch (epi): issued first; validate's vmcnt(0) drains it.
    float xf[4][4];
    if (epi) {
      const float* xb = out + (size_t)t * HT + obase;
#pragma unroll
      for (int jf = 0; jf < 4; ++jf)
#pragma unroll
        for (int r = 0; r < 4; ++r) {
          const float* p = xb + (size_t)r * H_DIM;
          asm volatile("global_load_dword %0, %1, off offset:%2"
                       : "=&v"(xf[jf][r]) : "v"(p), "i"(jf * 64));
        }
    }

    // ---- load + validate h chunk (the whole sync protocol) ----
    const unsigned* __restrict__ hp = hrow + (size_t)(t & 1) * HT;
    uint32x4 tq[16];
    for (;;) {
#pragma unroll
      for (int kc = 0; kc < 8; ++kc) {
        asm volatile("global_load_dwordx4 %0, %1, off offset:%2 sc0 sc1"
                     : "=&v"(tq[2 * kc]) : "v"(hp), "i"(kc * 128));
        asm volatile("global_load_dwordx4 %0, %1, off offset:%2 sc0 sc1"
                     : "=&v"(tq[2 * kc + 1]) : "v"(hp), "i"(kc * 128 + 16));
      }
      asm volatile("s_waitcnt vmcnt(0)" ::: "memory");
      __builtin_amdgcn_sched_barrier(0);   // rule #18
      unsigned bad = 0;
#pragma unroll
      for (int i = 0; i < 16; ++i) {
        bad |= tq[i].x ^ tagpat; bad |= tq[i].y ^ tagpat;
        bad |= tq[i].z ^ tagpat; bad |= tq[i].w ^ tagpat;
      }
      if (__all((bad & 0xFFFF0000u) == 0u)) break;
      __builtin_amdgcn_s_sleep(4);
    }
    __builtin_amdgcn_sched_barrier(0);

    // ---- strip tags -> bf16 fragments ----
    short8 hpk[8];
#pragma unroll
    for (int kc = 0; kc < 8; ++kc) {
      const uint32x4 a = tq[2 * kc], b = tq[2 * kc + 1];
      uint32x4 pk;
      pk.x = (a.x & 0xFFFFu) | (a.y << 16);
      pk.y = (a.z & 0xFFFFu) | (a.w << 16);
      pk.z = (b.x & 0xFFFFu) | (b.y << 16);
      pk.w = (b.z & 0xFFFFu) | (b.w << 16);
      hpk[kc] = __builtin_bit_cast(short8, pk);
    }

    // ---- MFMA: 4 jf x 8 kc, W from LDS ----
    f32x4 acc[4];
#pragma unroll
    for (int jf = 0; jf < 4; ++jf) acc[jf] = (f32x4){0.f, 0.f, 0.f, 0.f};
#pragma unroll
    for (int kc = 0; kc < 8; ++kc)
#pragma unroll
      for (int jf = 0; jf < 4; ++jf)
        acc[jf] = __builtin_amdgcn_mfma_f32_16x16x32_bf16(
            hpk[kc], w_lds[((kq * 8 + kc) * 4 + jf) * 64 + lane], acc[jf], 0, 0, 0);

    __syncthreads();   // bar A: epilogue(t-1) finished reading red
    if (!epi) {
#pragma unroll
      for (int jf = 0; jf < 4; ++jf)
#pragma unroll
        for (int r = 0; r < 4; ++r)
          red[kq - 1][mt][q * 4 + r][jf * 16 + ln] = acc[jf][r];
    }
    __syncthreads();   // bar B: partials visible

    if (epi) {
      const unsigned ntag = (unsigned)(t + 1) << 16;
      unsigned* __restrict__ hn = hTag + (size_t)((t + 1) & 1) * HT;
      float* __restrict__ xio = out + (size_t)t * HT;
#pragma unroll
      for (int jf = 0; jf < 4; ++jf)
#pragma unroll
        for (int r = 0; r < 4; ++r) {
          const int bl = q * 4 + r, jl = jf * 16 + ln;
          const float rec = acc[jf][r] + red[0][mt][bl][jl]
                          + red[1][mt][bl][jl] + red[2][mt][bl][jl];
          float x = 0.9f * hcur[jf][r] + 0.1f * (rec + bj[jf] + xf[jf][r]);
          x = x > 0.f ? x : 0.f;
          hcur[jf][r] = x;
          const size_t oidx = obase + (size_t)r * H_DIM + jf * 16;
          // tagged h: self-validating, no drain/flag needed.
          __hip_atomic_store(&hn[oidx], ntag | (unsigned)f2bf(x),
                             __ATOMIC_RELAXED, __HIP_MEMORY_SCOPE_AGENT);
          xio[oidx] = x;   // plain cached fp32 output
        }
    }
  }
}

// ---------------------------------------------------------------------------
extern "C" void kernel_launch(void* const* d_in, const int* in_sizes, int n_in,
                              void* d_out, int out_size, void* d_ws, size_t ws_size,
                              hipStream_t stream) {
  const float* input = (const float*)d_in[0];
  const float* W_in  = (const float*)d_in[1];
  const float* b_in  = (const float*)d_in[2];
  const float* W_hh  = (const float*)d_in[3];
  const float* b_hh  = (const float*)d_in[4];
  const float* h0    = (const float*)d_in[5];
  float* out = (float*)d_out;

  // ws layout (bytes):
  //   [0,  2M)   Wb    bf16 [1024][1024]
  //   [2M, 3M)   hTag  tagged h ping-pong, 2 x 512 KB
  //   [3M, 3.5M) Wih   bf16-hi W_in ; [3.5M,4M) Wil bf16-lo
  //   [4M, 20M)  Ah    bf16-hi input ; [20M,36M) Al bf16-lo
  char* ws = (char*)d_ws;
  unsigned short* Wb  = (unsigned short*)ws;
  unsigned*       hTg = (unsigned*)(ws + (2u << 20));
  unsigned short* Wih = (unsigned short*)(ws + (3u << 20));
  unsigned short* Wil = (unsigned short*)(ws + (7u << 19));   // 3.5 MB
  unsigned short* Ah  = (unsigned short*)(ws + (4u << 20));
  unsigned short* Al  = (unsigned short*)(ws + (20u << 20));

  cvt_w_bf16<<<(H_DIM * H_DIM / 4) / 256, 256, 0, stream>>>(W_hh, Wb);
  init_htag<<<(B_DIM * H_DIM) / 256, 256, 0, stream>>>(h0, hTg);

  if (ws_size >= (36u << 20)) {
    cvt_hi_lo<<<(T_LEN * B_DIM * I_DIM / 4) / 256, 256, 0, stream>>>(input, Ah, Al);
    cvt_hi_lo<<<(H_DIM * I_DIM / 4) / 256, 256, 0, stream>>>(W_in, Wih, Wil);
    dim3 g1(H_DIM / 64, (T_LEN * B_DIM) / 128);
    xproj_mfma<<<g1, 256, 0, stream>>>(Ah, Al, Wih, Wil, b_in, out);
  } else {
    dim3 g1(H_DIM / 64, (T_LEN * B_DIM) / 64);
    xproj_gemm<<<g1, 256, 0, stream>>>(input, W_in, b_in, out);
  }

  {
    unsigned* hTg_ = hTg;
    const unsigned short* Wb_ = Wb;
    const float* bhh_ = b_hh;
    const float* h0_ = h0;
    float* out_ = out;
    void* pargs[5] = {(void*)&hTg_, (void*)&Wb_, (void*)&bhh_, (void*)&h0_, (void*)&out_};
    hipLaunchCooperativeKernel((const void*)rnn_persist, dim3(64), dim3(512),
                               pargs, 0, stream);
  }
}